// Round 6
// baseline (771.815 us; speedup 1.0000x reference)
//
#include <hip/hip_runtime.h>
#include <hip/hip_bf16.h>

#define B_SZ 16
#define CIN 256
#define EDIM 256
#define NE 8192
#define HW 32
#define NPIX (B_SZ*HW*HW)          // 16384
#define OUT_ELEMS (B_SZ*CIN*HW*HW) // 4194304
#define SCREEN_T 3.2e-4f
#define CAND_SLOTS 128

typedef __attribute__((ext_vector_type(8))) short short8;
typedef __attribute__((ext_vector_type(4))) short short4v;
typedef __attribute__((ext_vector_type(4))) float f32x4;

// ---------------- helpers ----------------
__device__ __forceinline__ float block_sum(float v, float* sbuf) {
    #pragma unroll
    for (int off = 32; off > 0; off >>= 1) v += __shfl_down(v, off, 64);
    int wid = threadIdx.x >> 6;
    int lane = threadIdx.x & 63;
    if (lane == 0) sbuf[wid] = v;
    __syncthreads();
    if (threadIdx.x == 0) sbuf[0] = sbuf[0] + sbuf[1] + sbuf[2] + sbuf[3];
    __syncthreads();
    float r = sbuf[0];
    __syncthreads();
    return r;
}

__device__ __forceinline__ double block_sum_d(double v, double* sbuf) {
    #pragma unroll
    for (int off = 32; off > 0; off >>= 1) v += __shfl_down(v, off, 64);
    int wid = threadIdx.x >> 6;
    int lane = threadIdx.x & 63;
    if (lane == 0) sbuf[wid] = v;
    __syncthreads();
    if (threadIdx.x == 0) sbuf[0] = (sbuf[0] + sbuf[1]) + (sbuf[2] + sbuf[3]);
    __syncthreads();
    double r = sbuf[0];
    __syncthreads();
    return r;
}

__device__ __forceinline__ unsigned short bf16rne(float f) {
    unsigned int u = __float_as_uint(f);
    unsigned int r = (u + 0x7FFFu + ((u >> 16) & 1u)) >> 16;
    return (unsigned short)r;
}
__device__ __forceinline__ float bf2f(unsigned short h) {
    return __uint_as_float((unsigned int)h << 16);
}

// monotone map float -> uint (order-preserving), and inverse
__device__ __forceinline__ unsigned int mapU(float f) {
    unsigned int u = __float_as_uint(f);
    return (u & 0x80000000u) ? ~u : (u | 0x80000000u);
}
__device__ __forceinline__ float unmapU(unsigned int m) {
    unsigned int u = (m & 0x80000000u) ? (m ^ 0x80000000u) : ~m;
    return __uint_as_float(u);
}

// ---------------- weight repack: dst[k*256 + o] = src[o*2304 + k] ----------------
__global__ void repack_w_kernel(const float* __restrict__ src, float* __restrict__ dst) {
    int k = blockIdx.x;      // 0..2303
    int o = threadIdx.x;     // 0..255
    dst[(size_t)k * 256 + o] = src[(size_t)o * 2304 + k];
}

// ---------------- unemb weights -> bf16 hi/lo, tap-major: d[cout][tap*256+e] ----------------
__global__ void w2bf_kernel(const float* __restrict__ src, unsigned short* __restrict__ dhi,
                            unsigned short* __restrict__ dlo) {
    int blk = blockIdx.x;        // cout*9 + tap
    int cout = blk / 9, tap = blk % 9;
    int e = threadIdx.x;
    float v = src[(size_t)cout * 2304 + e * 9 + tap];
    unsigned short h = bf16rne(v);
    unsigned short l = bf16rne(v - bf2f(h));
    size_t j = (size_t)cout * 2304 + tap * 256 + e;
    dhi[j] = h; dlo[j] = l;
}

// ---------------- codebook -> bf16 hi/lo ----------------
__global__ void cbbf_kernel(const float* __restrict__ cb, unsigned short* __restrict__ cb_hi,
                            unsigned short* __restrict__ cb_lo) {
    int i = blockIdx.x * 256 + threadIdx.x;   // 0..524287
    size_t base = (size_t)i * 4;
    float4 v = *(const float4*)(cb + base);
    short4v sh, sl;
    unsigned short h;
    h = bf16rne(v.x); sh[0] = (short)h; sl[0] = (short)bf16rne(v.x - bf2f(h));
    h = bf16rne(v.y); sh[1] = (short)h; sl[1] = (short)bf16rne(v.y - bf2f(h));
    h = bf16rne(v.z); sh[2] = (short)h; sl[2] = (short)bf16rne(v.z - bf2f(h));
    h = bf16rne(v.w); sh[3] = (short)h; sl[3] = (short)bf16rne(v.w - bf2f(h));
    *(short4v*)(cb_hi + base) = sh;
    *(short4v*)(cb_lo + base) = sl;
}

// ---------------- emb conv: z[B,C,H,W] -> ze[(b,h,w), e] ----------------
// Per-output FMA chain (r0kw0,r0kw1,r0kw2,r1kw0,...) identical to validated rounds;
// accumulation: continuous fp32 FMA chain within 16-c groups, f64 fold per group
// (delta vs f64-per-c ~1e-7 on ze -> delta-dot ~1e-10, 30x below tolerated numpy gap).
// All accumulators in named registers (no arrays -> no scratch).
#define FMA_S0(vA, vB, ww, ff) ff.x=fmaf(vA.x,ww,ff.x); ff.y=fmaf(vA.y,ww,ff.y); ff.z=fmaf(vA.z,ww,ff.z); ff.w=fmaf(vA.w,ww,ff.w);
#define FMA_S1(vA, vB, ww, ff) ff.x=fmaf(vA.y,ww,ff.x); ff.y=fmaf(vA.z,ww,ff.y); ff.z=fmaf(vA.w,ww,ff.z); ff.w=fmaf(vB.x,ww,ff.w);
#define FMA_S2(vA, vB, ww, ff) ff.x=fmaf(vA.z,ww,ff.x); ff.y=fmaf(vA.w,ww,ff.y); ff.z=fmaf(vB.x,ww,ff.z); ff.w=fmaf(vB.y,ww,ff.w);

__global__ __launch_bounds__(256, 2) void conv_emb_kernel(const float* __restrict__ z,
                                                          const float* __restrict__ w1t,
                                                          const float* __restrict__ bias,
                                                          float* __restrict__ ze) {
    __shared__ float s[3 * 64 * 36];
    int bh = blockIdx.x;            // 0..511
    int b = bh >> 5, h = bh & 31;
    int e = (blockIdx.y << 7) + (threadIdx.x & 127);
    int wh = threadIdx.x >> 7;      // 0..1
    double2 d0a = {0.0, 0.0}, d0b = {0.0, 0.0};
    double2 d1a = {0.0, 0.0}, d1b = {0.0, 0.0};
    double2 d2a = {0.0, 0.0}, d2b = {0.0, 0.0};
    double2 d3a = {0.0, 0.0}, d3b = {0.0, 0.0};
    for (int i = threadIdx.x; i < 3 * 64 * 36; i += 256) s[i] = 0.f;
    __syncthreads();

    for (int cc = 0; cc < 256; cc += 64) {
        for (int i = threadIdx.x; i < 3 * 64 * 32; i += 256) {
            int r = i >> 11;
            int c = (i >> 5) & 63;
            int w = i & 31;
            int hh = h + r - 1;
            float v = 0.f;
            if (hh >= 0 && hh < 32) v = z[(size_t)b * 262144 + (size_t)(cc + c) * 1024 + hh * 32 + w];
            s[(r * 64 + c) * 36 + (w + 1)] = v;
        }
        __syncthreads();
        const float* wbase = w1t + (size_t)cc * 2304 + e;
        for (int c0 = 0; c0 < 64; c0 += 16) {
            float4 f0 = {0.f, 0.f, 0.f, 0.f}, f1 = {0.f, 0.f, 0.f, 0.f};
            float4 f2 = {0.f, 0.f, 0.f, 0.f}, f3 = {0.f, 0.f, 0.f, 0.f};
            for (int cu = 0; cu < 16; ++cu) {
                int c = c0 + cu;
                const float* wrow = wbase + (size_t)c * 2304;
                #pragma unroll
                for (int r = 0; r < 3; ++r) {
                    const float* lrow = s + (r * 64 + c) * 36 + wh * 16;
                    float4 v0 = *(const float4*)(lrow);
                    float4 v1 = *(const float4*)(lrow + 4);
                    float4 v2 = *(const float4*)(lrow + 8);
                    float4 v3 = *(const float4*)(lrow + 12);
                    float4 v4 = *(const float4*)(lrow + 16);
                    float w0 = wrow[(r * 3 + 0) * 256];
                    float w1 = wrow[(r * 3 + 1) * 256];
                    float w2 = wrow[(r * 3 + 2) * 256];
                    FMA_S0(v0, v1, w0, f0); FMA_S0(v1, v2, w0, f1); FMA_S0(v2, v3, w0, f2); FMA_S0(v3, v4, w0, f3);
                    FMA_S1(v0, v1, w1, f0); FMA_S1(v1, v2, w1, f1); FMA_S1(v2, v3, w1, f2); FMA_S1(v3, v4, w1, f3);
                    FMA_S2(v0, v1, w2, f0); FMA_S2(v1, v2, w2, f1); FMA_S2(v2, v3, w2, f2); FMA_S2(v3, v4, w2, f3);
                }
            }
            d0a.x += (double)f0.x; d0a.y += (double)f0.y; d0b.x += (double)f0.z; d0b.y += (double)f0.w;
            d1a.x += (double)f1.x; d1a.y += (double)f1.y; d1b.x += (double)f1.z; d1b.y += (double)f1.w;
            d2a.x += (double)f2.x; d2a.y += (double)f2.y; d2b.x += (double)f2.z; d2b.y += (double)f2.w;
            d3a.x += (double)f3.x; d3a.y += (double)f3.y; d3b.x += (double)f3.z; d3b.y += (double)f3.w;
        }
        __syncthreads();
    }
    float bv = bias[e];
    int p0 = (b * 32 + h) * 32 + wh * 16;
    ze[(size_t)(p0 +  0) * 256 + e] = (float)d0a.x + bv;
    ze[(size_t)(p0 +  1) * 256 + e] = (float)d0a.y + bv;
    ze[(size_t)(p0 +  2) * 256 + e] = (float)d0b.x + bv;
    ze[(size_t)(p0 +  3) * 256 + e] = (float)d0b.y + bv;
    ze[(size_t)(p0 +  4) * 256 + e] = (float)d1a.x + bv;
    ze[(size_t)(p0 +  5) * 256 + e] = (float)d1a.y + bv;
    ze[(size_t)(p0 +  6) * 256 + e] = (float)d1b.x + bv;
    ze[(size_t)(p0 +  7) * 256 + e] = (float)d1b.y + bv;
    ze[(size_t)(p0 +  8) * 256 + e] = (float)d2a.x + bv;
    ze[(size_t)(p0 +  9) * 256 + e] = (float)d2a.y + bv;
    ze[(size_t)(p0 + 10) * 256 + e] = (float)d2b.x + bv;
    ze[(size_t)(p0 + 11) * 256 + e] = (float)d2b.y + bv;
    ze[(size_t)(p0 + 12) * 256 + e] = (float)d3a.x + bv;
    ze[(size_t)(p0 + 13) * 256 + e] = (float)d3a.y + bv;
    ze[(size_t)(p0 + 14) * 256 + e] = (float)d3b.x + bv;
    ze[(size_t)(p0 + 15) * 256 + e] = (float)d3b.y + bv;
}

// ---------------- layernorm: emits zf_bf16, snorm, mu, rstd ----------------
__global__ void ln_kernel(const float* __restrict__ ze, const float* __restrict__ g,
                          const float* __restrict__ bta, unsigned short* __restrict__ zfb,
                          float* __restrict__ snorm, float* __restrict__ mu_a,
                          float* __restrict__ r_a) {
    __shared__ double sbuf[4];
    int p = blockIdx.x; int t = threadIdx.x;
    float x = ze[(size_t)p * 256 + t];
    double sum = block_sum_d((double)x, sbuf);
    float mu = ((float)sum) / 256.0f;
    float dev = x - mu;
    float sq = dev * dev;
    double vs = block_sum_d((double)sq, sbuf);
    float var = ((float)vs) / 256.0f;
    float r = 1.0f / sqrtf(var + 1e-5f);
    float y = ((dev * r) * g[t]) + bta[t];
    zfb[(size_t)p * 256 + t] = bf16rne(y);
    float ysq = y * y;
    double ss = block_sum_d((double)ysq, sbuf);
    if (t == 0) { snorm[p] = (float)ss; mu_a[p] = mu; r_a[p] = r; }
}

// ---------------- single-pass screening: B streamed from L2, no LDS tile, no main-loop barriers ----
__global__ __launch_bounds__(512) void screen_kernel(const unsigned short* __restrict__ zf_bf,
                                                     const unsigned short* __restrict__ cb_bf,
                                                     int* __restrict__ ccnt,
                                                     int* __restrict__ cand) {
    __shared__ unsigned int smax[64];
    __shared__ int scnt[64];
    __shared__ int sbuf[64][CAND_SLOTS];   // 32 KB
    const int tid = threadIdx.x;
    const int w = tid >> 6;
    const int lane = tid & 63;
    const int l15 = lane & 15, lg = lane >> 4;
    const int p0 = blockIdx.x * 64;
    const int rowoff = w * 16 + l15;
    const int lg8 = lg * 8;

    if (tid < 64) { smax[tid] = 0u; scnt[tid] = 0; }
    __syncthreads();

    short8 aF[4][8];
    #pragma unroll
    for (int mf = 0; mf < 4; ++mf)
        #pragma unroll
        for (int ks = 0; ks < 8; ++ks)
            aF[mf][ks] = *reinterpret_cast<const short8*>(
                zf_bf + (size_t)(p0 + mf * 16 + l15) * 256 + ks * 32 + lg8);

    const f32x4 zero4 = {0.f, 0.f, 0.f, 0.f};
    float runL[4][4], runS[4][4];
    #pragma unroll
    for (int mf = 0; mf < 4; ++mf)
        #pragma unroll
        for (int r = 0; r < 4; ++r) { runL[mf][r] = -3.4e38f; runS[mf][r] = -3.4e38f; }

    // ---- seed pass: n = 0..1023, max only ----
    for (int c = 0; c < 8; ++c) {
        const int nrow = c * 128 + rowoff;
        const unsigned short* bp = cb_bf + (size_t)nrow * 256 + lg8;
        short8 bF[8];
        #pragma unroll
        for (int ks = 0; ks < 8; ++ks) bF[ks] = *reinterpret_cast<const short8*>(bp + ks * 32);
        f32x4 acc[4] = {zero4, zero4, zero4, zero4};
        #pragma unroll
        for (int ks = 0; ks < 8; ++ks)
            #pragma unroll
            for (int mf = 0; mf < 4; ++mf)
                acc[mf] = __builtin_amdgcn_mfma_f32_16x16x32_bf16(aF[mf][ks], bF[ks], acc[mf], 0, 0, 0);
        #pragma unroll
        for (int mf = 0; mf < 4; ++mf)
            #pragma unroll
            for (int r = 0; r < 4; ++r) runL[mf][r] = fmaxf(runL[mf][r], acc[mf][r]);
    }
    #pragma unroll
    for (int mf = 0; mf < 4; ++mf)
        #pragma unroll
        for (int r = 0; r < 4; ++r) {
            float v = runL[mf][r];
            v = fmaxf(v, __shfl_xor(v, 1, 64));
            v = fmaxf(v, __shfl_xor(v, 2, 64));
            v = fmaxf(v, __shfl_xor(v, 4, 64));
            v = fmaxf(v, __shfl_xor(v, 8, 64));
            runL[mf][r] = v;
            if (l15 == 0) atomicMax(&smax[mf * 16 + lg * 4 + r], mapU(v));
        }
    __syncthreads();
    #pragma unroll
    for (int mf = 0; mf < 4; ++mf)
        #pragma unroll
        for (int r = 0; r < 4; ++r) runS[mf][r] = unmapU(smax[mf * 16 + lg * 4 + r]);

    // ---- main pass: all n, with collection ----
    for (int c = 0; c < 64; ++c) {
        const int nrow = c * 128 + rowoff;
        const unsigned short* bp = cb_bf + (size_t)nrow * 256 + lg8;
        short8 bF[8];
        #pragma unroll
        for (int ks = 0; ks < 8; ++ks) bF[ks] = *reinterpret_cast<const short8*>(bp + ks * 32);
        f32x4 acc[4] = {zero4, zero4, zero4, zero4};
        #pragma unroll
        for (int ks = 0; ks < 8; ++ks)
            #pragma unroll
            for (int mf = 0; mf < 4; ++mf)
                acc[mf] = __builtin_amdgcn_mfma_f32_16x16x32_bf16(aF[mf][ks], bF[ks], acc[mf], 0, 0, 0);

        unsigned qual = 0u;
        #pragma unroll
        for (int mf = 0; mf < 4; ++mf)
            #pragma unroll
            for (int r = 0; r < 4; ++r) {
                float dd = acc[mf][r];
                if (dd >= fmaxf(runS[mf][r], runL[mf][r]) - SCREEN_T) qual |= (1u << (mf * 4 + r));
                runL[mf][r] = fmaxf(runL[mf][r], dd);
            }
        if (qual) {
            #pragma unroll
            for (int mf = 0; mf < 4; ++mf)
                #pragma unroll
                for (int r = 0; r < 4; ++r)
                    if (qual & (1u << (mf * 4 + r))) {
                        int pix = mf * 16 + lg * 4 + r;
                        int s = atomicAdd(&scnt[pix], 1);
                        if (s < CAND_SLOTS) sbuf[pix][s] = nrow;
                    }
        }
        if ((c & 7) == 7) {
            #pragma unroll
            for (int mf = 0; mf < 4; ++mf)
                #pragma unroll
                for (int r = 0; r < 4; ++r) {
                    float v = runL[mf][r];
                    v = fmaxf(v, __shfl_xor(v, 1, 64));
                    v = fmaxf(v, __shfl_xor(v, 2, 64));
                    v = fmaxf(v, __shfl_xor(v, 4, 64));
                    v = fmaxf(v, __shfl_xor(v, 8, 64));
                    runL[mf][r] = v;
                    if (l15 == 0) atomicMax(&smax[mf * 16 + lg * 4 + r], mapU(v));
                }
            #pragma unroll
            for (int mf = 0; mf < 4; ++mf)
                #pragma unroll
                for (int r = 0; r < 4; ++r) runS[mf][r] = unmapU(smax[mf * 16 + lg * 4 + r]);
        }
    }
    __syncthreads();
    if (tid < 64) ccnt[p0 + tid] = (scnt[tid] < CAND_SLOTS) ? scnt[tid] : CAND_SLOTS;
    for (int i = tid; i < 64 * CAND_SLOTS; i += 512) {
        int pix = i >> 7;                 // CAND_SLOTS == 128
        int s = i & (CAND_SLOTS - 1);
        if (s < scnt[pix] && s < CAND_SLOTS)
            cand[(size_t)(p0 + pix) * CAND_SLOTS + s] = sbuf[pix][s];
    }
}

// ---------------- exact rescore (bit-identical to round-2 dist arithmetic) ----------------
__global__ __launch_bounds__(256) void rescore_kernel(const float* __restrict__ ze,
                                                      const float* __restrict__ mu_a,
                                                      const float* __restrict__ r_a,
                                                      const float* __restrict__ snorm,
                                                      const float* __restrict__ g,
                                                      const float* __restrict__ bta,
                                                      const float* __restrict__ cb,
                                                      const int* __restrict__ ccnt,
                                                      const int* __restrict__ cand,
                                                      int* __restrict__ idx_i,
                                                      float* __restrict__ idx_f) {
    int p = blockIdx.x * 4 + (threadIdx.x >> 6);
    int lane = threadIdx.x & 63;
    int cnt = ccnt[p];
    if (cnt > CAND_SLOTS) cnt = CAND_SLOTS;
    float d = 3.4e38f;
    int ix = 0x7FFFFFFF;
    float mu = mu_a[p];
    float r = r_a[p];
    float sz = snorm[p];
    const float* zr = ze + (size_t)p * 256;
    for (int s = lane; s < cnt; s += 64) {
        int n = cand[(size_t)p * CAND_SLOTS + s];
        const float* cr = cb + (size_t)n * 256;
        float a0 = 0.f, a1 = 0.f, a2 = 0.f, a3 = 0.f;
        for (int k0 = 0; k0 < 256; k0 += 4) {
            float4 zq = *(const float4*)(zr + k0);
            float4 gq = *(const float4*)(g + k0);
            float4 bq = *(const float4*)(bta + k0);
            float4 cq = *(const float4*)(cr + k0);
            float d0 = zq.x - mu; float y0 = ((d0 * r) * gq.x) + bq.x;
            float d1 = zq.y - mu; float y1 = ((d1 * r) * gq.y) + bq.y;
            float d2 = zq.z - mu; float y2 = ((d2 * r) * gq.z) + bq.z;
            float d3 = zq.w - mu; float y3 = ((d3 * r) * gq.w) + bq.w;
            a0 = fmaf(y0, cq.x, a0);
            a1 = fmaf(y1, cq.y, a1);
            a2 = fmaf(y2, cq.z, a2);
            a3 = fmaf(y3, cq.w, a3);
        }
        float dot32 = (float)(((double)a0 + (double)a1) + ((double)a2 + (double)a3));
        float dd = fmaf(-2.0f, dot32, sz);
        if (dd < d || (dd == d && n < ix)) { d = dd; ix = n; }
    }
    #pragma unroll
    for (int off = 32; off > 0; off >>= 1) {
        float ov = __shfl_down(d, off, 64);
        int   oi = __shfl_down(ix, off, 64);
        if (ov < d || (ov == d && oi < ix)) { d = ov; ix = oi; }
    }
    if (lane == 0) {
        idx_i[p] = ix;
        idx_f[p] = (float)ix;
    }
}

// ---------------- loss ----------------
__global__ void loss_partial_kernel(const float* __restrict__ ze, const float* __restrict__ cb,
                                    const int* __restrict__ idx, float* __restrict__ partials) {
    __shared__ float sbuf[4];
    float sum = 0.f;
    const int total = NPIX * 256;
    for (int i = blockIdx.x * blockDim.x + threadIdx.x; i < total; i += gridDim.x * blockDim.x) {
        int p = i >> 8;
        int e = i & 255;
        float d = cb[(size_t)idx[p] * 256 + e] - ze[i];
        sum = fmaf(d, d, sum);
    }
    sum = block_sum(sum, sbuf);
    if (threadIdx.x == 0) partials[blockIdx.x] = sum;
}

__global__ void loss_final_kernel(const float* __restrict__ partials, float* __restrict__ loss_out) {
    __shared__ float sbuf[4];
    float v = partials[threadIdx.x];
    v = block_sum(v, sbuf);
    if (threadIdx.x == 0) *loss_out = v * (1.25f / (float)(NPIX * 256));
}

// ---------------- unemb conv as split-bf16 MFMA implicit GEMM ----------------
#define AROWB 128
#define ALO   13056
__global__ __launch_bounds__(256, 4) void conv_unemb_mfma(const unsigned short* __restrict__ cb_hi,
                                                          const unsigned short* __restrict__ cb_lo,
                                                          const int* __restrict__ idx,
                                                          const unsigned short* __restrict__ w2_hi,
                                                          const unsigned short* __restrict__ w2_lo,
                                                          const float* __restrict__ bias,
                                                          float* __restrict__ out) {
    __shared__ char smem[2 * ALO];
    float* ot = (float*)smem;
    const int tid = threadIdx.x;
    const int wid = tid >> 6, lane = tid & 63;
    const int l15 = lane & 15, lg = lane >> 4;
    const int bh = blockIdx.x;
    const int b = bh >> 5, h = bh & 31;
    const int ch = blockIdx.y;

    for (int i = tid; i < (2 * ALO) / 16; i += 256) ((int4*)smem)[i] = make_int4(0, 0, 0, 0);

    int nrow[3], rok[3], wpos[3], rr3[3];
    #pragma unroll
    for (int rd = 0; rd < 3; ++rd) {
        int t2 = rd * 256 + tid;
        int row = t2 >> 3;
        int r = row >> 5, w = row & 31;
        int hh = h + r - 1;
        rok[rd] = (hh >= 0 && hh < 32) ? 1 : 0;
        rr3[rd] = r; wpos[rd] = w;
        nrow[rd] = rok[rd] ? idx[(b * 32 + hh) * 32 + w] : 0;
    }
    __syncthreads();

    const f32x4 zero4 = {0.f, 0.f, 0.f, 0.f};
    f32x4 acc[2][2];
    acc[0][0] = zero4; acc[0][1] = zero4; acc[1][0] = zero4; acc[1][1] = zero4;

    for (int ec = 0; ec < 4; ++ec) {
        if (ec) __syncthreads();
        #pragma unroll
        for (int rd = 0; rd < 3; ++rd) {
            if (rok[rd]) {
                int t2 = rd * 256 + tid;
                int eo = (t2 & 7) * 8;
                size_t gsrc = (size_t)nrow[rd] * 256 + ec * 64 + eo;
                short8 vh = *(const short8*)(cb_hi + gsrc);
                short8 vl = *(const short8*)(cb_lo + gsrc);
                int wp = wpos[rd] + 1;
                int rowbase = (rr3[rd] * 34 + wp) * AROWB;
                int boff = (eo * 2) ^ ((wp & 7) << 4);
                *(short8*)(smem + rowbase + boff) = vh;
                *(short8*)(smem + ALO + rowbase + boff) = vl;
            }
        }
        __syncthreads();

        #pragma unroll
        for (int tap = 0; tap < 9; ++tap) {
            const int r = tap / 3, kw = tap % 3;
            #pragma unroll
            for (int ks = 0; ks < 2; ++ks) {
                int e2 = ks * 32 + lg * 8;
                short8 ah[2], al[2], bh2[2], bl2[2];
                #pragma unroll
                for (int mf = 0; mf < 2; ++mf) {
                    int wp = mf * 16 + l15 + kw;
                    int rowbase = (r * 34 + wp) * AROWB;
                    int boff = (e2 * 2) ^ ((wp & 7) << 4);
                    ah[mf] = *(const short8*)(smem + rowbase + boff);
                    al[mf] = *(const short8*)(smem + ALO + rowbase + boff);
                }
                #pragma unroll
                for (int nf = 0; nf < 2; ++nf) {
                    int cout = (ch << 7) + (wid << 5) + (nf << 4) + l15;
                    size_t goff = (size_t)cout * 2304 + tap * 256 + ec * 64 + e2;
                    bh2[nf] = *(const short8*)(w2_hi + goff);
                    bl2[nf] = *(const short8*)(w2_lo + goff);
                }
                #pragma unroll
                for (int mf = 0; mf < 2; ++mf)
                    #pragma unroll
                    for (int nf = 0; nf < 2; ++nf) {
                        acc[mf][nf] = __builtin_amdgcn_mfma_f32_16x16x32_bf16(ah[mf], bh2[nf], acc[mf][nf], 0, 0, 0);
                        acc[mf][nf] = __builtin_amdgcn_mfma_f32_16x16x32_bf16(ah[mf], bl2[nf], acc[mf][nf], 0, 0, 0);
                        acc[mf][nf] = __builtin_amdgcn_mfma_f32_16x16x32_bf16(al[mf], bh2[nf], acc[mf][nf], 0, 0, 0);
                    }
            }
        }
    }
    __syncthreads();
    #pragma unroll
    for (int mf = 0; mf < 2; ++mf)
        #pragma unroll
        for (int nf = 0; nf < 2; ++nf) {
            int cl = (wid << 5) + (nf << 4) + l15;
            #pragma unroll
            for (int rr = 0; rr < 4; ++rr) {
                int px = mf * 16 + lg * 4 + rr;
                ot[cl * 36 + px] = acc[mf][nf][rr];
            }
        }
    __syncthreads();
    int row = tid >> 1, half = tid & 1;
    int cout = (ch << 7) + row;
    float bv = bias[cout];
    float* dst = out + ((size_t)(b * 256 + cout) * 32 + h) * 32 + half * 16;
    const float* src = ot + row * 36 + half * 16;
    #pragma unroll
    for (int q = 0; q < 4; ++q) {
        float4 v = *(const float4*)(src + q * 4);
        v.x += bv; v.y += bv; v.z += bv; v.w += bv;
        *(float4*)(dst + q * 4) = v;
    }
}

extern "C" void kernel_launch(void* const* d_in, const int* in_sizes, int n_in,
                              void* d_out, int out_size, void* d_ws, size_t ws_size,
                              hipStream_t stream) {
    const float* z       = (const float*)d_in[0];
    const float* emb_w   = (const float*)d_in[1];
    const float* emb_b   = (const float*)d_in[2];
    const float* ln_g    = (const float*)d_in[3];
    const float* ln_b    = (const float*)d_in[4];
    const float* cb      = (const float*)d_in[5];
    const float* unemb_w = (const float*)d_in[6];
    const float* unemb_b = (const float*)d_in[7];

    float* out    = (float*)d_out;                    // [16,256,32,32]
    float* lossp  = out + OUT_ELEMS;                  // scalar
    float* idxf   = out + OUT_ELEMS + 1;              // [16384] as float

    // workspace layout (float slots), total ~47 MB
    float* ws = (float*)d_ws;
    float* ze_t = ws;                                               // 4,194,304
    unsigned short* zf_bf = (unsigned short*)(ze_t + (size_t)NPIX * 256);      // 2,097,152 fl
    unsigned short* cb_hi = (unsigned short*)((float*)zf_bf + 2097152);        // 1,048,576 fl
    unsigned short* cb_lo = (unsigned short*)((float*)cb_hi + 1048576);        // 1,048,576 fl
    float* snorm = (float*)cb_lo + 1048576;                         // 16,384
    float* mu_a  = snorm + NPIX;                                    // 16,384
    float* r_a   = mu_a + NPIX;                                     // 16,384
    float* w1t   = r_a + NPIX;                                      // 589,824
    unsigned short* w2_hi = (unsigned short*)(w1t + 2304 * 256);    // 294,912 fl
    unsigned short* w2_lo = (unsigned short*)((float*)w2_hi + 294912); // 294,912 fl
    int*   ccnt  = (int*)((float*)w2_lo + 294912);                  // 16,384
    int*   cand  = ccnt + NPIX;                                     // 2,097,152
    int*   idxi  = cand + (size_t)NPIX * CAND_SLOTS;                // 16,384
    float* partials = (float*)(idxi + NPIX);                        // 256

    hipLaunchKernelGGL(repack_w_kernel, dim3(2304), dim3(256), 0, stream, emb_w, w1t);
    hipLaunchKernelGGL(w2bf_kernel, dim3(2304), dim3(256), 0, stream, unemb_w, w2_hi, w2_lo);
    hipLaunchKernelGGL(cbbf_kernel, dim3(2048), dim3(256), 0, stream, cb, cb_hi, cb_lo);
    hipLaunchKernelGGL(conv_emb_kernel, dim3(512, 2), dim3(256), 0, stream, z, w1t, emb_b, ze_t);
    hipLaunchKernelGGL(ln_kernel, dim3(NPIX), dim3(256), 0, stream, ze_t, ln_g, ln_b,
                       zf_bf, snorm, mu_a, r_a);
    hipLaunchKernelGGL(screen_kernel, dim3(256), dim3(512), 0, stream, zf_bf, cb_hi, ccnt, cand);
    hipLaunchKernelGGL(rescore_kernel, dim3(NPIX / 4), dim3(256), 0, stream,
                       ze_t, mu_a, r_a, snorm, ln_g, ln_b, cb, ccnt, cand, idxi, idxf);
    hipLaunchKernelGGL(loss_partial_kernel, dim3(256), dim3(256), 0, stream, ze_t, cb, idxi, partials);
    hipLaunchKernelGGL(loss_final_kernel, dim3(1), dim3(256), 0, stream, partials, lossp);
    hipLaunchKernelGGL(conv_unemb_mfma, dim3(512, 2), dim3(256), 0, stream,
                       cb_hi, cb_lo, idxi, w2_hi, w2_lo, unemb_b, out);
}